// Round 1
// baseline (271.826 us; speedup 1.0000x reference)
//
#include <hip/hip_runtime.h>
#include <hip/hip_bf16.h>

typedef unsigned short u16;
typedef short bf16x8 __attribute__((ext_vector_type(8)));
typedef float f32x4 __attribute__((ext_vector_type(4)));

#define NB 8
#define NH 8
#define QL 1024
#define KL 1024
#define DKD 64
#define LNEPS 1e-5f

__device__ __forceinline__ u16 to_bf16(float f) {
  unsigned u = __float_as_uint(f);
  unsigned r = u + 0x7FFFu + ((u >> 16) & 1u);
  return (u16)(r >> 16);
}
__device__ __forceinline__ float bf16_f32(u16 h) {
  return __uint_as_float(((unsigned)h) << 16);
}

// ---- prep: K -> khi/klo bf16 planes (same layout) ----
__global__ __launch_bounds__(256) void prep_k(const float* __restrict__ K,
                                              u16* __restrict__ khi, u16* __restrict__ klo) {
  int i = (blockIdx.x * 256 + threadIdx.x) * 4;
  float4 v = *reinterpret_cast<const float4*>(K + i);
  float f[4] = {v.x, v.y, v.z, v.w};
  u16 hh[4], ll[4];
#pragma unroll
  for (int j = 0; j < 4; ++j) {
    hh[j] = to_bf16(f[j]);
    ll[j] = to_bf16(f[j] - bf16_f32(hh[j]));
  }
  *reinterpret_cast<ushort4*>(khi + i) = make_ushort4(hh[0], hh[1], hh[2], hh[3]);
  *reinterpret_cast<ushort4*>(klo + i) = make_ushort4(ll[0], ll[1], ll[2], ll[3]);
}

// ---- prep: V[bh][k][d] f32 -> vt[bh][d][k] bf16 (transpose) ----
__global__ __launch_bounds__(256) void prep_v(const float* __restrict__ V, u16* __restrict__ vt) {
  __shared__ float t[32][33];
  const int bh = blockIdx.z, k0 = blockIdx.x * 32, d0 = blockIdx.y * 32;
  const float* src = V + (bh * KL + k0) * DKD + d0;
#pragma unroll
  for (int j = 0; j < 4; ++j) {
    int kk = threadIdx.y * 4 + j;
    t[kk][threadIdx.x] = src[kk * DKD + threadIdx.x];
  }
  __syncthreads();
  u16* dst = vt + (bh * DKD + d0) * KL + k0;
#pragma unroll
  for (int j = 0; j < 4; ++j) {
    int dd = threadIdx.y * 4 + j;
    dst[dd * KL + threadIdx.x] = to_bf16(t[threadIdx.x][dd]);
  }
}

// ---- pass 1: rowsum[bh][q] = sum_k exp(s) ----
__global__ __launch_bounds__(256) void stats_kernel(const float* __restrict__ Qm,
    const u16* __restrict__ khi, const u16* __restrict__ klo, float* __restrict__ rowsum) {
  const int lane = threadIdx.x & 63;
  const int w = threadIdx.x >> 6;
  const int bh = blockIdx.y;
  const int q0 = blockIdx.x * 64 + w * 16;
  const int m = lane & 15, g = lane >> 4;

  bf16x8 qh[2], ql[2];
#pragma unroll
  for (int dc = 0; dc < 2; ++dc) {
    const float* qp = Qm + ((bh * QL) + q0 + m) * DKD + dc * 32 + g * 8;
    float4 a = *reinterpret_cast<const float4*>(qp);
    float4 c = *reinterpret_cast<const float4*>(qp + 4);
    float f[8] = {a.x, a.y, a.z, a.w, c.x, c.y, c.z, c.w};
#pragma unroll
    for (int e = 0; e < 8; ++e) {
      float s = f[e] * 0.125f;
      u16 hi = to_bf16(s);
      qh[dc][e] = (short)hi;
      ql[dc][e] = (short)to_bf16(s - bf16_f32(hi));
    }
  }
  float part[4] = {0.f, 0.f, 0.f, 0.f};
  for (int kt = 0; kt < 64; ++kt) {
    const int k0 = kt * 16;
    const u16* kb = khi + ((bh * KL) + k0 + m) * DKD + g * 8;
    const u16* lb = klo + ((bh * KL) + k0 + m) * DKD + g * 8;
    bf16x8 kh0 = *reinterpret_cast<const bf16x8*>(kb);
    bf16x8 kh1 = *reinterpret_cast<const bf16x8*>(kb + 32);
    bf16x8 kl0 = *reinterpret_cast<const bf16x8*>(lb);
    bf16x8 kl1 = *reinterpret_cast<const bf16x8*>(lb + 32);
    f32x4 acc = {0.f, 0.f, 0.f, 0.f};
    acc = __builtin_amdgcn_mfma_f32_16x16x32_bf16(qh[0], kh0, acc, 0, 0, 0);
    acc = __builtin_amdgcn_mfma_f32_16x16x32_bf16(qh[0], kl0, acc, 0, 0, 0);
    acc = __builtin_amdgcn_mfma_f32_16x16x32_bf16(ql[0], kh0, acc, 0, 0, 0);
    acc = __builtin_amdgcn_mfma_f32_16x16x32_bf16(qh[1], kh1, acc, 0, 0, 0);
    acc = __builtin_amdgcn_mfma_f32_16x16x32_bf16(qh[1], kl1, acc, 0, 0, 0);
    acc = __builtin_amdgcn_mfma_f32_16x16x32_bf16(ql[1], kh1, acc, 0, 0, 0);
#pragma unroll
    for (int r = 0; r < 4; ++r) part[r] += __expf(acc[r]);
  }
#pragma unroll
  for (int r = 0; r < 4; ++r) {
    part[r] += __shfl_xor(part[r], 1);
    part[r] += __shfl_xor(part[r], 2);
    part[r] += __shfl_xor(part[r], 4);
    part[r] += __shfl_xor(part[r], 8);
  }
  if (m == 0) {
#pragma unroll
    for (int r = 0; r < 4; ++r) rowsum[bh * QL + q0 + g * 4 + r] = part[r];
  }
}

// ---- pass 2: fused S -> p -> head-mix -> LN -> att_map + PV ----
__global__ __launch_bounds__(512) void main_kernel(
    const float* __restrict__ Qm, const u16* __restrict__ khi, const u16* __restrict__ klo,
    const u16* __restrict__ vt, const float* __restrict__ rowsum,
    const float* __restrict__ hA, const float* __restrict__ lnw, const float* __restrict__ lnb,
    float* __restrict__ outp, float* __restrict__ att_map) {
  __shared__ __align__(16) float p_lds[NH][32][40];
  const int tid = threadIdx.x;
  const int lane = tid & 63, h = tid >> 6;
  const int b = blockIdx.y, q0 = blockIdx.x * 32;
  const int bh = b * NH + h;
  const int m = lane & 15, g = lane >> 4;

  // uniform params (scalar loads)
  float haR[64], wR[8], bR[8];
#pragma unroll
  for (int j = 0; j < 64; ++j) haR[j] = hA[j];
#pragma unroll
  for (int j = 0; j < 8; ++j) { wR[j] = lnw[j]; bR[j] = lnb[j]; }

  // Q fragments (hi/lo split, pre-scaled by 1/sqrt(dk))
  bf16x8 qh[2][2], ql[2][2];
#pragma unroll
  for (int r = 0; r < 2; ++r)
#pragma unroll
    for (int dc = 0; dc < 2; ++dc) {
      const float* qp = Qm + ((bh * QL) + q0 + r * 16 + m) * DKD + dc * 32 + g * 8;
      float4 a = *reinterpret_cast<const float4*>(qp);
      float4 c = *reinterpret_cast<const float4*>(qp + 4);
      float f[8] = {a.x, a.y, a.z, a.w, c.x, c.y, c.z, c.w};
#pragma unroll
      for (int e = 0; e < 8; ++e) {
        float s = f[e] * 0.125f;
        u16 hi = to_bf16(s);
        qh[r][dc][e] = (short)hi;
        ql[r][dc][e] = (short)to_bf16(s - bf16_f32(hi));
      }
    }
  float inv_rs[2][4];
#pragma unroll
  for (int r = 0; r < 2; ++r)
#pragma unroll
    for (int ri = 0; ri < 4; ++ri)
      inv_rs[r][ri] = 1.0f / rowsum[bh * QL + q0 + r * 16 + g * 4 + ri];

  f32x4 zero4 = {0.f, 0.f, 0.f, 0.f};
  f32x4 oacc[2][4];
#pragma unroll
  for (int r = 0; r < 2; ++r)
#pragma unroll
    for (int dt = 0; dt < 4; ++dt) oacc[r][dt] = zero4;

  for (int kt = 0; kt < 32; ++kt) {
    const int k0 = kt * 32;
    // --- S phase: s = Q K^T / 8, p = exp(s)/rowsum -> LDS ---
    bf16x8 kh[2][2], kl[2][2];
#pragma unroll
    for (int c = 0; c < 2; ++c)
#pragma unroll
      for (int dc = 0; dc < 2; ++dc) {
        kh[c][dc] = *reinterpret_cast<const bf16x8*>(khi + ((bh * KL) + k0 + c * 16 + m) * DKD + dc * 32 + g * 8);
        kl[c][dc] = *reinterpret_cast<const bf16x8*>(klo + ((bh * KL) + k0 + c * 16 + m) * DKD + dc * 32 + g * 8);
      }
#pragma unroll
    for (int r = 0; r < 2; ++r)
#pragma unroll
      for (int c = 0; c < 2; ++c) {
        f32x4 acc = zero4;
        acc = __builtin_amdgcn_mfma_f32_16x16x32_bf16(qh[r][0], kh[c][0], acc, 0, 0, 0);
        acc = __builtin_amdgcn_mfma_f32_16x16x32_bf16(qh[r][0], kl[c][0], acc, 0, 0, 0);
        acc = __builtin_amdgcn_mfma_f32_16x16x32_bf16(ql[r][0], kh[c][0], acc, 0, 0, 0);
        acc = __builtin_amdgcn_mfma_f32_16x16x32_bf16(qh[r][1], kh[c][1], acc, 0, 0, 0);
        acc = __builtin_amdgcn_mfma_f32_16x16x32_bf16(qh[r][1], kl[c][1], acc, 0, 0, 0);
        acc = __builtin_amdgcn_mfma_f32_16x16x32_bf16(ql[r][1], kh[c][1], acc, 0, 0, 0);
#pragma unroll
        for (int ri = 0; ri < 4; ++ri)
          p_lds[h][r * 16 + g * 4 + ri][c * 16 + m] = __expf(acc[ri]) * inv_rs[r][ri];
      }
    __syncthreads();
    // --- mix + LN + att_map (each (q,k) position by exactly one thread) ---
#pragma unroll
    for (int rep = 0; rep < 2; ++rep) {
      const int pos = tid + rep * 512;
      const int qq = pos >> 5, kk = pos & 31;
      float p8[8];
#pragma unroll
      for (int j = 0; j < 8; ++j) p8[j] = p_lds[j][qq][kk];
      float mixed[8];
      float mu = 0.f;
#pragma unroll
      for (int hh = 0; hh < 8; ++hh) {
        float s = 0.f;
#pragma unroll
        for (int j = 0; j < 8; ++j) s = fmaf(p8[j], haR[j * 8 + hh], s);
        mixed[hh] = s;
        mu += s;
      }
      mu *= 0.125f;
      float var = 0.f;
#pragma unroll
      for (int hh = 0; hh < 8; ++hh) { float d = mixed[hh] - mu; var = fmaf(d, d, var); }
      var *= 0.125f;
      const float rs = rsqrtf(var + LNEPS);
      float am = 0.f;
#pragma unroll
      for (int hh = 0; hh < 8; ++hh) {
        float y = (mixed[hh] - mu) * rs * wR[hh] + bR[hh];
        am += y;
        p_lds[hh][qq][kk] = y;  // in-place: this position owned by this thread
      }
      att_map[((size_t)b * QL + (q0 + qq)) * KL + k0 + kk] = am * 0.125f;
    }
    __syncthreads();
    // --- PV phase: out += y * V (A = y from LDS, B = vt bf16 contiguous) ---
#pragma unroll
    for (int r = 0; r < 2; ++r) {
      const float* yp = &p_lds[h][r * 16 + m][g * 8];
      float4 y0 = *reinterpret_cast<const float4*>(yp);
      float4 y1 = *reinterpret_cast<const float4*>(yp + 4);
      float yf[8] = {y0.x, y0.y, y0.z, y0.w, y1.x, y1.y, y1.z, y1.w};
      bf16x8 af;
#pragma unroll
      for (int e = 0; e < 8; ++e) af[e] = (short)to_bf16(yf[e]);
#pragma unroll
      for (int dt = 0; dt < 4; ++dt) {
        bf16x8 vb = *reinterpret_cast<const bf16x8*>(vt + ((bh * DKD) + dt * 16 + m) * KL + k0 + g * 8);
        oacc[r][dt] = __builtin_amdgcn_mfma_f32_16x16x32_bf16(af, vb, oacc[r][dt], 0, 0, 0);
      }
    }
    __syncthreads();
  }
#pragma unroll
  for (int r = 0; r < 2; ++r)
#pragma unroll
    for (int dt = 0; dt < 4; ++dt)
#pragma unroll
      for (int ri = 0; ri < 4; ++ri)
        outp[((bh * QL) + q0 + r * 16 + g * 4 + ri) * DKD + dt * 16 + m] = oacc[r][dt][ri];
}

extern "C" void kernel_launch(void* const* d_in, const int* in_sizes, int n_in,
                              void* d_out, int out_size, void* d_ws, size_t ws_size,
                              hipStream_t stream) {
  const float* Qm  = (const float*)d_in[0];
  const float* Km  = (const float*)d_in[1];
  const float* Vm  = (const float*)d_in[2];
  const float* hA  = (const float*)d_in[3];
  const float* lnw = (const float*)d_in[4];
  const float* lnb = (const float*)d_in[5];
  float* outp = (float*)d_out;
  float* att_map = outp + (size_t)64 * QL * DKD;

  char* ws = (char*)d_ws;
  float* rowsum = (float*)ws;                                  // 64*1024*4 = 256 KB
  u16* khi = (u16*)(ws + 262144);                              // 8 MB
  u16* klo = (u16*)(ws + 262144 + 8388608);                    // 8 MB
  u16* vt  = (u16*)(ws + 262144 + 2 * 8388608);                // 8 MB

  prep_k<<<4096, 256, 0, stream>>>(Km, khi, klo);
  prep_v<<<dim3(32, 2, 64), dim3(32, 8), 0, stream>>>(Vm, vt);
  stats_kernel<<<dim3(16, 64), 256, 0, stream>>>(Qm, khi, klo, rowsum);
  main_kernel<<<dim3(32, 8), 512, 0, stream>>>(Qm, khi, klo, vt, rowsum, hA, lnw, lnb, outp, att_map);
}

// Round 2
// 211.734 us; speedup vs baseline: 1.2838x; 1.2838x over previous
//
#include <hip/hip_runtime.h>
#include <hip/hip_bf16.h>

typedef _Float16 f16;
typedef f16 f16x8 __attribute__((ext_vector_type(8)));
typedef f16 f16x4 __attribute__((ext_vector_type(4)));
typedef float f32x4 __attribute__((ext_vector_type(4)));

#define QL 1024
#define KL 1024
#define DKD 64
#define NH 8
#define LNEPS 1e-5f

// ---- prep: K f32 -> f16 plane (same [bh][k][d] layout) ----
__global__ __launch_bounds__(256) void prep_kf(const float* __restrict__ K, f16* __restrict__ kf) {
  int i = (blockIdx.x * 256 + threadIdx.x) * 4;
  float4 v = *reinterpret_cast<const float4*>(K + i);
  f16x4 o;
  o[0] = (f16)v.x; o[1] = (f16)v.y; o[2] = (f16)v.z; o[3] = (f16)v.w;
  *reinterpret_cast<f16x4*>(kf + i) = o;
}

// ---- prep: V[bh][k][d] f32 -> vt[bh][d][k] f16 (transpose) ----
__global__ __launch_bounds__(256) void prep_vt(const float* __restrict__ V, f16* __restrict__ vt) {
  __shared__ float t[32][33];
  const int bh = blockIdx.z, k0 = blockIdx.x * 32, d0 = blockIdx.y * 32;
  const float* src = V + ((size_t)bh * KL + k0) * DKD + d0;
#pragma unroll
  for (int j = 0; j < 4; ++j) {
    int kk = threadIdx.y * 4 + j;
    t[kk][threadIdx.x] = src[kk * DKD + threadIdx.x];
  }
  __syncthreads();
  f16* dst = vt + ((size_t)bh * DKD + d0) * KL + k0;
#pragma unroll
  for (int j = 0; j < 4; ++j) {
    int dd = threadIdx.y * 4 + j;
    dst[dd * KL + threadIdx.x] = (f16)t[threadIdx.x][dd];
  }
}

// ---- fused: rowsum sweep + S -> p -> mix -> LN -> att_map + PV ----
// block = 256 thr (4 waves), covers (16 q-rows, batch b, all 8 heads, all k).
// wave w owns k-columns {kt*64 + w*16 + m} in sweep2 and heads {w, w+4} for PV.
__global__ __launch_bounds__(256, 2) void main_kernel(
    const float* __restrict__ Qm, const f16* __restrict__ kf, const f16* __restrict__ vt,
    const float* __restrict__ hA, const float* __restrict__ lnw, const float* __restrict__ lnb,
    float* __restrict__ outp, float* __restrict__ att_map) {
  __shared__ __align__(16) f16 y_lds[2][NH][16][64];
  __shared__ float rs_lds[4][NH][16];

  const int tid = threadIdx.x;
  const int lane = tid & 63, w = tid >> 6;
  const int m = lane & 15, g = lane >> 4;
  const int b = blockIdx.y, q0 = blockIdx.x * 16;

  // uniform params -> SGPRs (verified round 1: compiler scalarizes these)
  float haR[64], wR[8], bR[8];
#pragma unroll
  for (int j = 0; j < 64; ++j) haR[j] = hA[j];
#pragma unroll
  for (int j = 0; j < 8; ++j) { wR[j] = lnw[j]; bR[j] = lnb[j]; }

  // Q fragments for all 8 heads, fp16, pre-scaled by 1/sqrt(dk)
  f16x8 qf[NH][2];
#pragma unroll
  for (int h = 0; h < NH; ++h)
#pragma unroll
    for (int dc = 0; dc < 2; ++dc) {
      const float* qp = Qm + (((size_t)(b * NH + h)) * QL + q0 + m) * DKD + dc * 32 + g * 8;
      float4 a = *reinterpret_cast<const float4*>(qp);
      float4 c = *reinterpret_cast<const float4*>(qp + 4);
      f16x8 q;
      q[0] = (f16)(a.x * 0.125f); q[1] = (f16)(a.y * 0.125f);
      q[2] = (f16)(a.z * 0.125f); q[3] = (f16)(a.w * 0.125f);
      q[4] = (f16)(c.x * 0.125f); q[5] = (f16)(c.y * 0.125f);
      q[6] = (f16)(c.z * 0.125f); q[7] = (f16)(c.w * 0.125f);
      qf[h][dc] = q;
    }

  const size_t kbase_b = (size_t)b * NH * KL;   // row index base for this batch in kf

  // ---- sweep 1: partial rowsums over this wave's k slice [w*256, w*256+256) ----
  float prs[NH][4];
#pragma unroll
  for (int h = 0; h < NH; ++h)
#pragma unroll
    for (int ri = 0; ri < 4; ++ri) prs[h][ri] = 0.f;

  for (int t = 0; t < 16; ++t) {
    const int k0 = w * 256 + t * 16;
    const f16* kb = kf + (kbase_b + k0 + m) * DKD + g * 8;
#pragma unroll
    for (int h = 0; h < NH; ++h) {
      f16x8 k0f = *reinterpret_cast<const f16x8*>(kb + (size_t)h * KL * DKD);
      f16x8 k1f = *reinterpret_cast<const f16x8*>(kb + (size_t)h * KL * DKD + 32);
      f32x4 acc = {0.f, 0.f, 0.f, 0.f};
      acc = __builtin_amdgcn_mfma_f32_16x16x32_f16(qf[h][0], k0f, acc, 0, 0, 0);
      acc = __builtin_amdgcn_mfma_f32_16x16x32_f16(qf[h][1], k1f, acc, 0, 0, 0);
#pragma unroll
      for (int ri = 0; ri < 4; ++ri) prs[h][ri] += __expf(acc[ri]);
    }
  }
  // reduce over the 16 m-lanes (bits 0..3 of lane)
#pragma unroll
  for (int h = 0; h < NH; ++h)
#pragma unroll
    for (int ri = 0; ri < 4; ++ri) {
      float v = prs[h][ri];
      v += __shfl_xor(v, 1); v += __shfl_xor(v, 2);
      v += __shfl_xor(v, 4); v += __shfl_xor(v, 8);
      prs[h][ri] = v;
    }
  if (m == 0) {
#pragma unroll
    for (int h = 0; h < NH; ++h)
#pragma unroll
      for (int ri = 0; ri < 4; ++ri) rs_lds[w][h][g * 4 + ri] = prs[h][ri];
  }
  __syncthreads();
  float inv_rs[NH][4];
#pragma unroll
  for (int h = 0; h < NH; ++h)
#pragma unroll
    for (int ri = 0; ri < 4; ++ri) {
      int qq = g * 4 + ri;
      inv_rs[h][ri] = 1.0f / (rs_lds[0][h][qq] + rs_lds[1][h][qq] +
                              rs_lds[2][h][qq] + rs_lds[3][h][qq]);
    }

  f32x4 oacc[2][4];
#pragma unroll
  for (int hp = 0; hp < 2; ++hp)
#pragma unroll
    for (int dt = 0; dt < 4; ++dt) oacc[hp][dt] = (f32x4){0.f, 0.f, 0.f, 0.f};

  // ---- sweep 2: main loop over 16 tiles of k=64 ----
  for (int kt = 0; kt < 16; ++kt) {
    const int kbase = kt * 64;
    const int kcol = kbase + w * 16;          // this wave's S columns: kcol + m
    const int buf = kt & 1;

    // S phase: 8 heads, 16x16 tile each, columns kcol+m
    f32x4 pacc[NH];
    {
      const f16* kb = kf + (kbase_b + kcol + m) * DKD + g * 8;
#pragma unroll
      for (int h = 0; h < NH; ++h) {
        f16x8 k0f = *reinterpret_cast<const f16x8*>(kb + (size_t)h * KL * DKD);
        f16x8 k1f = *reinterpret_cast<const f16x8*>(kb + (size_t)h * KL * DKD + 32);
        f32x4 acc = {0.f, 0.f, 0.f, 0.f};
        acc = __builtin_amdgcn_mfma_f32_16x16x32_f16(qf[h][0], k0f, acc, 0, 0, 0);
        acc = __builtin_amdgcn_mfma_f32_16x16x32_f16(qf[h][1], k1f, acc, 0, 0, 0);
        pacc[h] = acc;
      }
    }
    // p = exp(s) * inv_rowsum  (all 8 heads of each (q,k) live in this lane)
#pragma unroll
    for (int h = 0; h < NH; ++h)
#pragma unroll
      for (int ri = 0; ri < 4; ++ri)
        pacc[h][ri] = __expf(pacc[h][ri]) * inv_rs[h][ri];

    // mix + LN + att_map + y -> LDS (swizzled)
#pragma unroll
    for (int ri = 0; ri < 4; ++ri) {
      const int qq = g * 4 + ri;
      float mixed[8];
      float mu = 0.f;
#pragma unroll
      for (int hh = 0; hh < 8; ++hh) {
        float s = 0.f;
#pragma unroll
        for (int j = 0; j < 8; ++j) s = fmaf(pacc[j][ri], haR[j * 8 + hh], s);
        mixed[hh] = s; mu += s;
      }
      mu *= 0.125f;
      float var = 0.f;
#pragma unroll
      for (int hh = 0; hh < 8; ++hh) { float d = mixed[hh] - mu; var = fmaf(d, d, var); }
      var *= 0.125f;
      const float rsv = rsqrtf(var + LNEPS);
      float am = 0.f;
      // storage swizzle: 16B-block index ^= (row&7); write k_local = w*16+m
      const int kidx = ((((2 * w + (m >> 3)) ^ (qq & 7)) << 3) | (m & 7));
#pragma unroll
      for (int hh = 0; hh < 8; ++hh) {
        float y = (mixed[hh] - mu) * rsv * wR[hh] + bR[hh];
        am += y;
        y_lds[buf][hh][qq][kidx] = (f16)y;
      }
      att_map[((size_t)b * QL + q0 + qq) * KL + kcol + m] = am * 0.125f;
    }
    __syncthreads();   // y tile complete (single barrier per k64 tile; dbuf covers WAR)

    // PV phase: this wave handles heads {w, w+4} over the full k64
#pragma unroll
    for (int hp = 0; hp < 2; ++hp) {
      const int hh = w + hp * 4;
      const f16* vb = vt + (((size_t)(b * NH + hh)) * DKD + m) * KL + kbase + g * 8;
#pragma unroll
      for (int ks = 0; ks < 2; ++ks) {
        const f16x8 af = *reinterpret_cast<const f16x8*>(
            &y_lds[buf][hh][m][((ks * 4 + g) ^ (m & 7)) << 3]);
#pragma unroll
        for (int dt = 0; dt < 4; ++dt) {
          f16x8 vf = *reinterpret_cast<const f16x8*>(vb + (size_t)dt * 16 * KL + ks * 32);
          oacc[hp][dt] = __builtin_amdgcn_mfma_f32_16x16x32_f16(af, vf, oacc[hp][dt], 0, 0, 0);
        }
      }
    }
  }

  // epilogue: store out (each wave owns heads w, w+4 completely)
#pragma unroll
  for (int hp = 0; hp < 2; ++hp) {
    const int hh = w + hp * 4;
#pragma unroll
    for (int dt = 0; dt < 4; ++dt)
#pragma unroll
      for (int ri = 0; ri < 4; ++ri)
        outp[(((size_t)(b * NH + hh)) * QL + q0 + g * 4 + ri) * DKD + dt * 16 + m] =
            oacc[hp][dt][ri];
  }
}

extern "C" void kernel_launch(void* const* d_in, const int* in_sizes, int n_in,
                              void* d_out, int out_size, void* d_ws, size_t ws_size,
                              hipStream_t stream) {
  const float* Qm  = (const float*)d_in[0];
  const float* Km  = (const float*)d_in[1];
  const float* Vm  = (const float*)d_in[2];
  const float* hA  = (const float*)d_in[3];
  const float* lnw = (const float*)d_in[4];
  const float* lnb = (const float*)d_in[5];
  float* outp = (float*)d_out;
  float* att_map = outp + (size_t)64 * QL * DKD;

  char* ws = (char*)d_ws;
  f16* kfp = (f16*)ws;                       // 64*1024*64*2B = 8 MB
  f16* vtp = (f16*)(ws + (size_t)8 * 1024 * 1024);  // 8 MB

  prep_kf<<<4096, 256, 0, stream>>>(Km, kfp);
  prep_vt<<<dim3(32, 2, 64), dim3(32, 8), 0, stream>>>(Vm, vtp);
  main_kernel<<<dim3(64, 8), 256, 0, stream>>>(Qm, kfp, vtp, hA, lnw, lnb, outp, att_map);
}